// Round 8
// baseline (1761.819 us; speedup 1.0000x reference)
//
#include <hip/hip_runtime.h>
#include <stdint.h>

// Problem constants (from reference)
#define N_USERS 100000
#define N_ITEMS 50000
#define N_NODES 150000
#define NNZ     4800000
#define DIM     64
#define NELEM   (N_NODES * DIM)   // 9,600,000
#define EPS_F   0.1f
#define RCAP    80   // per-row edge cap; P(Binom(4.8M,1/150K) > 80) ~ 4e-12/row

// Invariants established in rounds 0-7:
//  - all inputs f32; outputs f32; out = [all_mean | layer_embeddings]
//  - noise bits = o0 ^ o1 of threefry2x32(fold_in(key42,k), (0, flat_idx));
//    u = bitcast((bits>>9)|0x3f800000) - 1
//  - SpMM must accumulate per-row in ASCENDING EDGE ORDER with separate
//    __fmul_rn/__fadd_rn (matches np f32 sequential scatter-add; sign() would
//    amplify any reassociation into 0.02-scale errors)
//  - row L2-norm association is NOT load-bearing (noise perturbation only)

// ---------------------------------------------------------------------------
// JAX threefry2x32
// ---------------------------------------------------------------------------
__host__ __device__ inline void threefry2x32_fn(unsigned k0, unsigned k1,
                                                unsigned x0, unsigned x1,
                                                unsigned* o0, unsigned* o1) {
  unsigned ks0 = k0, ks1 = k1, ks2 = k0 ^ k1 ^ 0x1BD11BDAu;
  x0 += ks0; x1 += ks1;
#define TF_ROUND(r) { x0 += x1; x1 = (x1 << (r)) | (x1 >> (32 - (r))); x1 ^= x0; }
  TF_ROUND(13) TF_ROUND(15) TF_ROUND(26) TF_ROUND(6)
  x0 += ks1; x1 += ks2 + 1u;
  TF_ROUND(17) TF_ROUND(29) TF_ROUND(16) TF_ROUND(24)
  x0 += ks2; x1 += ks0 + 2u;
  TF_ROUND(13) TF_ROUND(15) TF_ROUND(26) TF_ROUND(6)
  x0 += ks0; x1 += ks1 + 3u;
  TF_ROUND(17) TF_ROUND(29) TF_ROUND(16) TF_ROUND(24)
  x0 += ks1; x1 += ks2 + 4u;
  TF_ROUND(13) TF_ROUND(15) TF_ROUND(26) TF_ROUND(6)
  x0 += ks2; x1 += ks0 + 5u;
#undef TF_ROUND
  *o0 = x0; *o1 = x1;
}

// ---------------------------------------------------------------------------
// Kernel 1: collect — scatter {col, edge_id} into padded per-row slots.
// pairs[r*RCAP+p] = (col<<32) | e   (p via atomic cursor; unordered)
// ---------------------------------------------------------------------------
__global__ void collect_kernel(const int* __restrict__ rows,
                               const int* __restrict__ cols,
                               int* __restrict__ cnt,
                               unsigned long long* __restrict__ pairs) {
  int e = blockIdx.x * 256 + threadIdx.x;   // grid covers NNZ exactly
  int r = rows[e];
  int c = cols[e];
  int p = atomicAdd(&cnt[r], 1);
  if (p < RCAP)
    pairs[(long long)r * RCAP + p] =
        ((unsigned long long)(unsigned)c << 32) | (unsigned)e;
}

// ---------------------------------------------------------------------------
// Kernel 2: sortk — per row (one wave): rank-sort by edge id ascending, then
// replace the edge-id field with vals[e]:  pairs[.] = (col<<32) | bits(val).
// Self-row in-place rewrite only -> no cross-block hazard.
// ---------------------------------------------------------------------------
__global__ void sortk_kernel(const float* __restrict__ vals,
                             const int* __restrict__ cnt,
                             unsigned long long* __restrict__ pairs) {
  __shared__ int se[4][RCAP];
  __shared__ int sc[4][RCAP];
  __shared__ int oe[4][RCAP];
  __shared__ int oc[4][RCAP];
  int wid  = threadIdx.x >> 6;
  int lane = threadIdx.x & 63;
  int row  = blockIdx.x * 4 + wid;          // grid covers N_NODES exactly
  int d = cnt[row]; if (d > RCAP) d = RCAP;
  long long base = (long long)row * RCAP;
  #pragma unroll
  for (int rep = 0; rep < 2; ++rep) {
    int j = lane + rep * 64;
    if (j < d) {
      unsigned long long pr = pairs[base + j];
      se[wid][j] = (int)(unsigned)(pr & 0xffffffffu);
      sc[wid][j] = (int)(unsigned)(pr >> 32);
    }
  }
  __syncthreads();
  #pragma unroll
  for (int rep = 0; rep < 2; ++rep) {
    int j = lane + rep * 64;
    if (j < d) {
      int my = se[wid][j];
      int rk = 0;
      for (int m = 0; m < RCAP; ++m)
        if (m < d && se[wid][m] < my) ++rk;
      oe[wid][rk] = my;
      oc[wid][rk] = sc[wid][j];
    }
  }
  __syncthreads();
  #pragma unroll
  for (int rep = 0; rep < 2; ++rep) {
    int j = lane + rep * 64;
    if (j < d) {
      float v = vals[oe[wid][j]];           // one-time random gather
      pairs[base + j] =
          ((unsigned long long)(unsigned)oc[wid][j] << 32) | __float_as_uint(v);
    }
  }
}

// ---------------------------------------------------------------------------
// Kernel 3: fused SpMM + noise + output epilogue. One wave per row, lane=dim.
// K-loop: wave-uniform broadcast read of sorted {val,col} pairs (contiguous),
// coalesced 256 B gather of src row, strict-order __fadd_rn accumulation.
// ---------------------------------------------------------------------------
template <int K>
__global__ void spmm_noise_kernel(const unsigned long long* __restrict__ pairs,
                                  const int* __restrict__ cnt,
                                  const float* __restrict__ user_e,
                                  const float* __restrict__ item_e,
                                  const float* __restrict__ src,
                                  float* __restrict__ dst,
                                  float* __restrict__ out_mean,
                                  unsigned key0, unsigned key1) {
  int wid  = threadIdx.x >> 6;
  int lane = threadIdx.x & 63;
  int row  = blockIdx.x * 4 + wid;          // grid covers N_NODES exactly
  int d = cnt[row]; if (d > RCAP) d = RCAP;
  const unsigned long long* prow = pairs + (long long)row * RCAP;

  float acc = 0.0f;
  for (int t = 0; t < d; ++t) {
    unsigned long long pr = prow[t];        // wave-uniform broadcast, L1-hot
    float v = __uint_as_float((unsigned)(pr & 0xffffffffu));
    int   c = (int)(unsigned)(pr >> 32);
    float x;
    if (K == 0) {                           // virtual concat(user, item)
      x = (c < N_USERS) ? user_e[(long long)c * DIM + lane]
                        : item_e[(long long)(c - N_USERS) * DIM + lane];
    } else {
      x = src[(long long)c * DIM + lane];
    }
    acc = __fadd_rn(acc, __fmul_rn(v, x));  // strict edge-order accumulation
  }

  // --- noise epilogue (exact JAX stream; norm association not load-bearing)
  int i = row * DIM + lane;
  unsigned o0, o1;
  threefry2x32_fn(key0, key1, 0u, (unsigned)i, &o0, &o1);
  unsigned bits = o0 ^ o1;
  float u = __uint_as_float((bits >> 9) | 0x3f800000u) - 1.0f;
  float ss = __fmul_rn(u, u);
  #pragma unroll
  for (int off = 32; off >= 1; off >>= 1)
    ss += __shfl_xor(ss, off, 64);
  float noise = u / sqrtf(ss);
  float s = (acc > 0.0f) ? 1.0f : ((acc < 0.0f) ? -1.0f : 0.0f);
  float val = __fadd_rn(acc, __fmul_rn(s, __fmul_rn(noise, EPS_F)));

  if (K == 0) {
    dst[i] = val;                           // dst == out_layer (hop-0 ego)
    out_mean[i] = val;
  } else if (K == 1) {
    dst[i] = val;                           // ws ego buffer for hop 2
    out_mean[i] = __fadd_rn(out_mean[i], val);
  } else {
    out_mean[i] = __fadd_rn(out_mean[i], val) / 3.0f;
  }
}

// ---------------------------------------------------------------------------
// Launch
// ---------------------------------------------------------------------------
extern "C" void kernel_launch(void* const* d_in, const int* in_sizes, int n_in,
                              void* d_out, int out_size, void* d_ws, size_t ws_size,
                              hipStream_t stream) {
  const float* user_e = (const float*)d_in[0];
  const float* item_e = (const float*)d_in[1];
  const int*   rows   = (const int*)d_in[2];
  const int*   cols   = (const int*)d_in[3];
  const float* vals   = (const float*)d_in[4];

  float* out_mean  = (float*)d_out;           // [all_mean: 150000 x 64]
  float* out_layer = (float*)d_out + NELEM;   // [layer_embeddings] == hop-0 ego

  // workspace: pairs 96,000,000 | ego 38,400,000 | cnt 600,000  = 135,000,000 B
  char* w = (char*)d_ws;
  unsigned long long* pairs = (unsigned long long*)w;
  float* ego = (float*)(w + 96000000);
  int*   cnt = (int*)(w + 96000000 + 38400000);

  // fold_in(key(42), k) = threefry((0,42),(0,k))
  unsigned hk0[3], hk1[3];
  for (int k = 0; k < 3; ++k)
    threefry2x32_fn(0u, 42u, 0u, (unsigned)k, &hk0[k], &hk1[k]);

  const int BT = 256;
  const unsigned edge_blocks = NNZ / BT;        // 18750 exact
  const unsigned row_blocks  = N_NODES / 4;     // 37500 exact (4 rows/block)

  hipMemsetAsync(cnt, 0, N_NODES * sizeof(int), stream);
  collect_kernel<<<edge_blocks, BT, 0, stream>>>(rows, cols, cnt, pairs);
  sortk_kernel<<<row_blocks, BT, 0, stream>>>(vals, cnt, pairs);

  spmm_noise_kernel<0><<<row_blocks, BT, 0, stream>>>(
      pairs, cnt, user_e, item_e, nullptr, out_layer, out_mean, hk0[0], hk1[0]);
  spmm_noise_kernel<1><<<row_blocks, BT, 0, stream>>>(
      pairs, cnt, nullptr, nullptr, out_layer, ego, out_mean, hk0[1], hk1[1]);
  spmm_noise_kernel<2><<<row_blocks, BT, 0, stream>>>(
      pairs, cnt, nullptr, nullptr, ego, nullptr, out_mean, hk0[2], hk1[2]);
}

// Round 9
// 1110.130 us; speedup vs baseline: 1.5870x; 1.5870x over previous
//
#include <hip/hip_runtime.h>
#include <stdint.h>

// Problem constants (from reference)
#define N_USERS 100000
#define N_ITEMS 50000
#define N_NODES 150000
#define NNZ     4800000
#define DIM     64
#define NELEM   (N_NODES * DIM)   // 9,600,000
#define EPS_F   0.1f
#define RCAP    80   // per-row edge cap; P(overflow) ~ 4e-12/row

// Invariants established in rounds 0-8:
//  - all inputs f32; outputs f32; out = [all_mean | layer_embeddings]
//  - noise bits = o0 ^ o1 of threefry2x32(fold_in(key42,k), (0, flat_idx));
//    u = bitcast((bits>>9)|0x3f800000) - 1
//  - SpMM must accumulate per-row in ASCENDING EDGE ORDER with separate
//    __fmul_rn/__fadd_rn (matches np f32 sequential scatter-add; sign()
//    amplifies any reassociation into 0.02-scale errors)
//  - row L2-norm association is NOT load-bearing
//  - R8 lesson: hops are LATENCY-bound (VGPR=8, 1 gather in flight, 453 us);
//    this round adds MLP (lane-parallel pairs + 4x unrolled gathers)

typedef unsigned long long ull;

// ---------------------------------------------------------------------------
// JAX threefry2x32
// ---------------------------------------------------------------------------
__host__ __device__ inline void threefry2x32_fn(unsigned k0, unsigned k1,
                                                unsigned x0, unsigned x1,
                                                unsigned* o0, unsigned* o1) {
  unsigned ks0 = k0, ks1 = k1, ks2 = k0 ^ k1 ^ 0x1BD11BDAu;
  x0 += ks0; x1 += ks1;
#define TF_ROUND(r) { x0 += x1; x1 = (x1 << (r)) | (x1 >> (32 - (r))); x1 ^= x0; }
  TF_ROUND(13) TF_ROUND(15) TF_ROUND(26) TF_ROUND(6)
  x0 += ks1; x1 += ks2 + 1u;
  TF_ROUND(17) TF_ROUND(29) TF_ROUND(16) TF_ROUND(24)
  x0 += ks2; x1 += ks0 + 2u;
  TF_ROUND(13) TF_ROUND(15) TF_ROUND(26) TF_ROUND(6)
  x0 += ks0; x1 += ks1 + 3u;
  TF_ROUND(17) TF_ROUND(29) TF_ROUND(16) TF_ROUND(24)
  x0 += ks1; x1 += ks2 + 4u;
  TF_ROUND(13) TF_ROUND(15) TF_ROUND(26) TF_ROUND(6)
  x0 += ks2; x1 += ks0 + 5u;
#undef TF_ROUND
  *o0 = x0; *o1 = x1;
}

// ---------------------------------------------------------------------------
// Kernel 1: collect — scatter {col, edge_id} into padded per-row slots.
// ---------------------------------------------------------------------------
__global__ void collect_kernel(const int* __restrict__ rows,
                               const int* __restrict__ cols,
                               int* __restrict__ cnt,
                               ull* __restrict__ pairs) {
  int e = blockIdx.x * 256 + threadIdx.x;   // grid covers NNZ exactly
  int r = rows[e];
  int c = cols[e];
  int p = atomicAdd(&cnt[r], 1);
  if (p < RCAP)
    pairs[(long long)r * RCAP + p] = ((ull)(unsigned)c << 32) | (unsigned)e;
}

// ---------------------------------------------------------------------------
// Kernel 2: sortk — per row (one wave): rank-sort by edge id ascending, then
// replace the edge-id field with vals[e]:  pairs[.] = (col<<32) | bits(val).
// ---------------------------------------------------------------------------
__global__ void sortk_kernel(const float* __restrict__ vals,
                             const int* __restrict__ cnt,
                             ull* __restrict__ pairs) {
  __shared__ int se[4][RCAP];
  __shared__ int sc[4][RCAP];
  __shared__ int oe[4][RCAP];
  __shared__ int oc[4][RCAP];
  int wid  = threadIdx.x >> 6;
  int lane = threadIdx.x & 63;
  int row  = blockIdx.x * 4 + wid;          // grid covers N_NODES exactly
  int d = cnt[row]; if (d > RCAP) d = RCAP;
  long long base = (long long)row * RCAP;
  #pragma unroll
  for (int rep = 0; rep < 2; ++rep) {
    int j = lane + rep * 64;
    if (j < d) {
      ull pr = pairs[base + j];
      se[wid][j] = (int)(unsigned)(pr & 0xffffffffu);
      sc[wid][j] = (int)(unsigned)(pr >> 32);
    }
  }
  __syncthreads();
  #pragma unroll
  for (int rep = 0; rep < 2; ++rep) {
    int j = lane + rep * 64;
    if (j < d) {
      int my = se[wid][j];
      int rk = 0;
      for (int m = 0; m < RCAP; ++m)
        if (m < d && se[wid][m] < my) ++rk;
      oe[wid][rk] = my;
      oc[wid][rk] = sc[wid][j];
    }
  }
  __syncthreads();
  #pragma unroll
  for (int rep = 0; rep < 2; ++rep) {
    int j = lane + rep * 64;
    if (j < d) {
      float v = vals[oe[wid][j]];           // one-time random gather
      pairs[base + j] = ((ull)(unsigned)oc[wid][j] << 32) | __float_as_uint(v);
    }
  }
}

// ---------------------------------------------------------------------------
// Kernel 3: fused SpMM + noise + output epilogue, MLP version.
// One wave per row, lane = dim. Pairs are read ONCE, lane-parallel (coalesced
// 512 B), then broadcast per-iteration via __shfl (wave-uniform t -> uniform
// {v,c}). Gathers unrolled 4x so >=4 random 256 B reads are in flight per
// wave; the strict-order __fadd_rn chain is unchanged.
// ---------------------------------------------------------------------------
template <int K>
__global__ void spmm_noise_kernel(const ull* __restrict__ pairs,
                                  const int* __restrict__ cnt,
                                  const float* __restrict__ user_e,
                                  const float* __restrict__ item_e,
                                  const float* __restrict__ src,
                                  float* __restrict__ dst,
                                  float* __restrict__ out_mean,
                                  unsigned key0, unsigned key1) {
  int wid  = threadIdx.x >> 6;
  int lane = threadIdx.x & 63;
  int row  = blockIdx.x * 4 + wid;          // grid covers N_NODES exactly
  int d = cnt[row]; if (d > RCAP) d = RCAP;
  const ull* prow = pairs + (long long)row * RCAP;

  // whole row's pairs -> registers (coalesced; slots >= d are never consumed)
  ull my0 = prow[lane];
  ull my1 = (64 + lane < RCAP) ? prow[64 + lane] : 0ULL;

  #define GET_PAIR(t) ((t) < 64 ? __shfl(my0, (t), 64) : __shfl(my1, (t) - 64, 64))

  #define GATHER(c, xout_) do {                                            \
    if (K == 0) {                                                          \
      xout_ = ((c) < N_USERS)                                              \
          ? user_e[(long long)(c) * DIM + lane]                            \
          : item_e[(long long)((c) - N_USERS) * DIM + lane];               \
    } else {                                                               \
      xout_ = src[(long long)(c) * DIM + lane];                            \
    }                                                                      \
  } while (0)

  float acc = 0.0f;
  int t = 0;
  for (; t + 4 <= d; t += 4) {
    ull p0 = GET_PAIR(t);
    ull p1 = GET_PAIR(t + 1);
    ull p2 = GET_PAIR(t + 2);
    ull p3 = GET_PAIR(t + 3);
    int c0 = (int)(unsigned)(p0 >> 32), c1 = (int)(unsigned)(p1 >> 32);
    int c2 = (int)(unsigned)(p2 >> 32), c3 = (int)(unsigned)(p3 >> 32);
    float x0, x1, x2, x3;
    GATHER(c0, x0); GATHER(c1, x1); GATHER(c2, x2); GATHER(c3, x3);
    float v0 = __uint_as_float((unsigned)(p0 & 0xffffffffu));
    float v1 = __uint_as_float((unsigned)(p1 & 0xffffffffu));
    float v2 = __uint_as_float((unsigned)(p2 & 0xffffffffu));
    float v3 = __uint_as_float((unsigned)(p3 & 0xffffffffu));
    acc = __fadd_rn(acc, __fmul_rn(v0, x0));   // strict ascending edge order
    acc = __fadd_rn(acc, __fmul_rn(v1, x1));
    acc = __fadd_rn(acc, __fmul_rn(v2, x2));
    acc = __fadd_rn(acc, __fmul_rn(v3, x3));
  }
  for (; t < d; ++t) {
    ull p = GET_PAIR(t);
    int c = (int)(unsigned)(p >> 32);
    float x;
    GATHER(c, x);
    float v = __uint_as_float((unsigned)(p & 0xffffffffu));
    acc = __fadd_rn(acc, __fmul_rn(v, x));
  }
  #undef GATHER
  #undef GET_PAIR

  // --- noise epilogue (exact JAX stream; norm association not load-bearing)
  int i = row * DIM + lane;
  unsigned o0, o1;
  threefry2x32_fn(key0, key1, 0u, (unsigned)i, &o0, &o1);
  unsigned bits = o0 ^ o1;
  float u = __uint_as_float((bits >> 9) | 0x3f800000u) - 1.0f;
  float ss = __fmul_rn(u, u);
  #pragma unroll
  for (int off = 32; off >= 1; off >>= 1)
    ss += __shfl_xor(ss, off, 64);
  float noise = u / sqrtf(ss);
  float s = (acc > 0.0f) ? 1.0f : ((acc < 0.0f) ? -1.0f : 0.0f);
  float val = __fadd_rn(acc, __fmul_rn(s, __fmul_rn(noise, EPS_F)));

  if (K == 0) {
    dst[i] = val;                           // dst == out_layer (hop-0 ego)
    out_mean[i] = val;
  } else if (K == 1) {
    dst[i] = val;                           // ws ego buffer for hop 2
    out_mean[i] = __fadd_rn(out_mean[i], val);
  } else {
    out_mean[i] = __fadd_rn(out_mean[i], val) / 3.0f;
  }
}

// ---------------------------------------------------------------------------
// Launch
// ---------------------------------------------------------------------------
extern "C" void kernel_launch(void* const* d_in, const int* in_sizes, int n_in,
                              void* d_out, int out_size, void* d_ws, size_t ws_size,
                              hipStream_t stream) {
  const float* user_e = (const float*)d_in[0];
  const float* item_e = (const float*)d_in[1];
  const int*   rows   = (const int*)d_in[2];
  const int*   cols   = (const int*)d_in[3];
  const float* vals   = (const float*)d_in[4];

  float* out_mean  = (float*)d_out;           // [all_mean: 150000 x 64]
  float* out_layer = (float*)d_out + NELEM;   // [layer_embeddings] == hop-0 ego

  // workspace: pairs 96,000,000 | ego 38,400,000 | cnt 600,000
  char* w = (char*)d_ws;
  ull*   pairs = (ull*)w;
  float* ego   = (float*)(w + 96000000);
  int*   cnt   = (int*)(w + 96000000 + 38400000);

  // fold_in(key(42), k) = threefry((0,42),(0,k))
  unsigned hk0[3], hk1[3];
  for (int k = 0; k < 3; ++k)
    threefry2x32_fn(0u, 42u, 0u, (unsigned)k, &hk0[k], &hk1[k]);

  const int BT = 256;
  const unsigned edge_blocks = NNZ / BT;        // 18750 exact
  const unsigned row_blocks  = N_NODES / 4;     // 37500 exact (4 rows/block)

  hipMemsetAsync(cnt, 0, N_NODES * sizeof(int), stream);
  collect_kernel<<<edge_blocks, BT, 0, stream>>>(rows, cols, cnt, pairs);
  sortk_kernel<<<row_blocks, BT, 0, stream>>>(vals, cnt, pairs);

  spmm_noise_kernel<0><<<row_blocks, BT, 0, stream>>>(
      pairs, cnt, user_e, item_e, nullptr, out_layer, out_mean, hk0[0], hk1[0]);
  spmm_noise_kernel<1><<<row_blocks, BT, 0, stream>>>(
      pairs, cnt, nullptr, nullptr, out_layer, ego, out_mean, hk0[1], hk1[1]);
  spmm_noise_kernel<2><<<row_blocks, BT, 0, stream>>>(
      pairs, cnt, nullptr, nullptr, ego, nullptr, out_mean, hk0[2], hk1[2]);
}